// Round 6
// baseline (31954.010 us; speedup 1.0000x reference)
//
#include <hip/hip_runtime.h>

typedef unsigned short u16;
typedef __attribute__((ext_vector_type(8))) short bf16x8;
typedef __attribute__((ext_vector_type(4))) float f32x4;

#define MFMA(a,b,c) __builtin_amdgcn_mfma_f32_16x16x32_bf16(a,b,c,0,0,0)

#define B_   128
#define T_   200
#define F_   171
#define FX_  256          // padded frame (8 K-chunks of 32; zero-padded weights)
#define H_   1024
#define G_   4096
#define TF_  (T_*F_)
#define BH_  (B_*H_)
#define NB_  256
#define NT_  512

__device__ __forceinline__ u16 f2bf(float v){
  union { float f; unsigned u; } c; c.f = v;
  unsigned r = (c.u + 0x7fffu + ((c.u >> 16) & 1u)) >> 16;   // RNE
  return (u16)r;
}
__device__ __forceinline__ float bf2f(u16 h){
  union { unsigned u; float f; } c; c.u = ((unsigned)h) << 16; return c.f;
}
__device__ __forceinline__ bf16x8 ld8(const u16* p){
  return *reinterpret_cast<const bf16x8*>(p);
}
__device__ __forceinline__ float sigm(float v){ return 1.f / (1.f + __expf(-v)); }

// ---------- device barrier: release-wb, hierarchical (16 leaves x 16), acquire-inv ----------
// Invalidate is cheap now: weights/c/bias live in REGISTERS; only h/if/W-streams refetch.
__device__ __forceinline__ void gbar(unsigned* bar, unsigned ep, int tid, int bid){
  __syncthreads();
  if (tid == 0){
    __builtin_amdgcn_fence(__ATOMIC_RELEASE, "agent");       // wb dirty L2 -> MALL
    unsigned* leaf = bar + (bid >> 4) * 16;
    unsigned* root = bar + 16 * 16;
    const unsigned old = atomicAdd(leaf, 1u);
    if (old == ep * 16u - 1u) atomicAdd(root, 1u);
    while (__hip_atomic_load(root, __ATOMIC_RELAXED, __HIP_MEMORY_SCOPE_AGENT) < ep * 16u)
      __builtin_amdgcn_s_sleep(1);
    __builtin_amdgcn_fence(__ATOMIC_ACQUIRE, "agent");       // inv stale L1/L2
  }
  __syncthreads();
}

// ---------- W2/W3 role: weight-resident HH layer, wave = 64 cols x 256 K, 2 batch rounds ----------
__device__ __forceinline__ void role_hh(
    int L, int ug, const u16* __restrict__ Wg, const float* __restrict__ bias_l,
    u16* __restrict__ h_hi, u16* __restrict__ h_lo,
    unsigned* __restrict__ bar, int tid, int bid, float (*red)[64][68])
{
  const int w = tid >> 6, lane = tid & 63, r16 = lane & 15, ke = lane >> 4;
  const int u = tid & 15, bq = tid >> 4;

  bf16x8 wr[4][8];                                   // 64 cols x 256 K resident (128 VGPR)
#pragma unroll
  for (int tt = 0; tt < 4; ++tt)
#pragma unroll
    for (int kc = 0; kc < 8; ++kc)
      wr[tt][kc] = ld8(Wg + (size_t)(ug*64 + tt*16 + r16)*2048 + w*256 + kc*32 + ke*8);

  float bias[4], cs[4] = {0.f, 0.f, 0.f, 0.f};       // c-state in registers
#pragma unroll
  for (int q = 0; q < 4; ++q) bias[q] = bias_l[ug*64 + q*16 + u];

  unsigned ep = 0;
  for (int t = 0; t < T_; ++t){
    const int cur = t & 1, prv = cur ^ 1;
    ++ep; gbar(bar, ep, tid, bid);                   // BAR1 (h0_cur ready)
    if (L == 2){ ++ep; gbar(bar, ep, tid, bid); }    // W3 also waits BAR2 (h1_cur)

    const u16* ah = (w < 4 ? h_hi + ((L-1)*2+cur)*BH_ : h_hi + (L*2+prv)*BH_) + (w&3)*256 + ke*8;
    const u16* al = (w < 4 ? h_lo + ((L-1)*2+cur)*BH_ : h_lo + (L*2+prv)*BH_) + (w&3)*256 + ke*8;
    u16* ohh = h_hi + (L*2+cur)*BH_;
    u16* ohl = h_lo + (L*2+cur)*BH_;

#pragma unroll
    for (int bh = 0; bh < 2; ++bh){                  // 2 rounds x 64 batches
      f32x4 acc[4][4];
#pragma unroll
      for (int a = 0; a < 4; ++a)
#pragma unroll
        for (int b = 0; b < 4; ++b) acc[a][b] = (f32x4){0,0,0,0};
#pragma unroll
      for (int kc = 0; kc < 8; ++kc){
#pragma unroll
        for (int bt = 0; bt < 4; ++bt){
          const int ao = (bh*64 + bt*16 + r16)*H_ + kc*32;
          const bf16x8 pa = ld8(ah + ao);
          const bf16x8 pl = ld8(al + ao);
#pragma unroll
          for (int tt = 0; tt < 4; ++tt){
            acc[bt][tt] = MFMA(pa, wr[tt][kc], acc[bt][tt]);
            acc[bt][tt] = MFMA(pl, wr[tt][kc], acc[bt][tt]);
          }
        }
      }
#pragma unroll
      for (int bt = 0; bt < 4; ++bt)
#pragma unroll
        for (int tt = 0; tt < 4; ++tt)
#pragma unroll
          for (int r = 0; r < 4; ++r)
            red[w][bt*16 + ke*4 + r][tt*16 + r16] = acc[bt][tt][r];
      __syncthreads();
#pragma unroll
      for (int j = 0; j < 2; ++j){                   // 2 cells/thread/round
        const int bl = bq*2 + j;
        float g[4];
#pragma unroll
        for (int q = 0; q < 4; ++q){
          float s = bias[q];
#pragma unroll
          for (int kw = 0; kw < 8; ++kw) s += red[kw][bl][q*16 + u];
          g[q] = s;
        }
        const int ci = bh*2 + j;
        const float cn = sigm(g[1])*cs[ci] + sigm(g[0])*tanhf(g[2]);
        const float hn = sigm(g[3])*tanhf(cn);
        cs[ci] = cn;
        const int idx = (bh*64 + bl)*H_ + ug*16 + u;
        const u16 hh = f2bf(hn);
        ohh[idx] = hh;
        ohl[idx] = f2bf(hn - bf2f(hh));
      }
      __syncthreads();
    }

    ++ep; gbar(bar, ep, tid, bid);                   // own-phase barrier
    if (L == 1){ ++ep; gbar(bar, ep, tid, bid); }    // W2 passes P3 barrier
    ++ep; gbar(bar, ep, tid, bid);                   // P4 barrier
  }
}

// ---------- main persistent kernel: 256 blocks x 512 thr, role by bid ----------
__global__ __launch_bounds__(NT_, 1) void k_main(
    const float* __restrict__ x, float* __restrict__ out,
    const u16* __restrict__ W1X, const u16* __restrict__ W1H,
    const u16* __restrict__ W2,  const u16* __restrict__ W3,
    const u16* __restrict__ WD,
    const float* __restrict__ bperm, const float* __restrict__ bdec,
    u16* __restrict__ h_hi, u16* __restrict__ h_lo,
    u16* __restrict__ if_hi, u16* __restrict__ if_lo,
    unsigned* __restrict__ bar)
{
  const int tid = threadIdx.x, bid = blockIdx.x;
  const int w = tid >> 6, lane = tid & 63, r16 = lane & 15, ke = lane >> 4;
  const int u = tid & 15, bq = tid >> 4;
  __shared__ float red[8][64][68];                   // 139 KB K-reduce buffer

  if (bid < 64){
    role_hh(1, bid, W2, bperm + 1*G_, h_hi, h_lo, bar, tid, bid, red);
  } else if (bid < 128){
    role_hh(2, bid - 64, W3, bperm + 2*G_, h_hi, h_lo, bar, tid, bid, red);
  } else if (bid < 192){
    // ---------------- W1 role: resident W1H (wave = 64b x 64c x 256K), streamed W1X ----------------
    const int ug = bid - 128;
    const int bh = w >> 2, kq = w & 3;
    bf16x8 wr[4][8];                                 // W1H: 64 cols x 256 K (quarter of 1024)
#pragma unroll
    for (int tt = 0; tt < 4; ++tt)
#pragma unroll
      for (int kc = 0; kc < 8; ++kc)
        wr[tt][kc] = ld8(W1H + (size_t)(ug*64 + tt*16 + r16)*1024 + kq*256 + kc*32 + ke*8);
    float bias[4], cs[4] = {0.f, 0.f, 0.f, 0.f};
#pragma unroll
    for (int q = 0; q < 4; ++q) bias[q] = bperm[0*G_ + ug*64 + q*16 + u];

    f32x4 acc[4][4];                                 // carried W1H*h0_prv partial
#pragma unroll
    for (int a = 0; a < 4; ++a)
#pragma unroll
      for (int b = 0; b < 4; ++b) acc[a][b] = (f32x4){0,0,0,0};

    unsigned ep = 0;
    for (int t = 0; t < T_; ++t){
      const int cur = t & 1;
      // ---- P1: add streamed W1X * if_frame, reduce, cell ----
#pragma unroll
      for (int kc = 0; kc < 2; ++kc){
        bf16x8 wx[4];
#pragma unroll
        for (int tt = 0; tt < 4; ++tt)
          wx[tt] = ld8(W1X + (size_t)(ug*64 + tt*16 + r16)*FX_ + kq*64 + kc*32 + ke*8);
#pragma unroll
        for (int bt = 0; bt < 4; ++bt){
          const int ao = (bh*64 + bt*16 + r16)*FX_ + kq*64 + kc*32 + ke*8;
          const bf16x8 pa = ld8(if_hi + ao);
          const bf16x8 pl = ld8(if_lo + ao);
#pragma unroll
          for (int tt = 0; tt < 4; ++tt){
            acc[bt][tt] = MFMA(pa, wx[tt], acc[bt][tt]);
            acc[bt][tt] = MFMA(pl, wx[tt], acc[bt][tt]);
          }
        }
      }
#pragma unroll
      for (int bt = 0; bt < 4; ++bt)
#pragma unroll
        for (int tt = 0; tt < 4; ++tt)
#pragma unroll
          for (int r = 0; r < 4; ++r)
            red[w][bt*16 + ke*4 + r][tt*16 + r16] = acc[bt][tt][r];
      __syncthreads();
      {
        u16* ohh = h_hi + (0*2+cur)*BH_;
        u16* ohl = h_lo + (0*2+cur)*BH_;
#pragma unroll
        for (int j = 0; j < 4; ++j){                 // 4 cells/thread
          const int b = bq*4 + j;
          float g[4];
#pragma unroll
          for (int q = 0; q < 4; ++q){
            float s = bias[q];
#pragma unroll
            for (int k4 = 0; k4 < 4; ++k4) s += red[(b>>6)*4 + k4][b & 63][q*16 + u];
            g[q] = s;
          }
          const float cn = sigm(g[1])*cs[j] + sigm(g[0])*tanhf(g[2]);
          const float hn = sigm(g[3])*tanhf(cn);
          cs[j] = cn;
          const int idx = b*H_ + ug*16 + u;
          const u16 hh = f2bf(hn);
          ohh[idx] = hh;
          ohl[idx] = f2bf(hn - bf2f(hh));
        }
      }
      ++ep; gbar(bar, ep, tid, bid);                 // BAR1

      // ---- P2 (parallel): W1H * h0_cur -> carried acc for t+1 ----
#pragma unroll
      for (int a = 0; a < 4; ++a)
#pragma unroll
        for (int b = 0; b < 4; ++b) acc[a][b] = (f32x4){0,0,0,0};
      {
        const u16* ah = h_hi + (0*2+cur)*BH_ + kq*256 + ke*8;
        const u16* al = h_lo + (0*2+cur)*BH_ + kq*256 + ke*8;
#pragma unroll
        for (int kc = 0; kc < 8; ++kc){
#pragma unroll
          for (int bt = 0; bt < 4; ++bt){
            const int ao = (bh*64 + bt*16 + r16)*H_ + kc*32;
            const bf16x8 pa = ld8(ah + ao);
            const bf16x8 pl = ld8(al + ao);
#pragma unroll
            for (int tt = 0; tt < 4; ++tt){
              acc[bt][tt] = MFMA(pa, wr[tt][kc], acc[bt][tt]);
              acc[bt][tt] = MFMA(pl, wr[tt][kc], acc[bt][tt]);
            }
          }
        }
      }
      ++ep; gbar(bar, ep, tid, bid);                 // BAR2
      ++ep; gbar(bar, ep, tid, bid);                 // BAR3
      ++ep; gbar(bar, ep, tid, bid);                 // BAR4
    }
  } else if (bid < 203){
    // ---------------- decoder role: 11 blocks x 16 cols, streamed WD ----------------
    const int ct = bid - 192;
    const int bh = w >> 2, kq = w & 3;
    const float bd = bdec[ct*16 + u];
    unsigned ep = 0;
    for (int t = 0; t < T_; ++t){
      const int cur = t & 1;
      ++ep; gbar(bar, ep, tid, bid);                 // BAR1
      ++ep; gbar(bar, ep, tid, bid);                 // BAR2
      ++ep; gbar(bar, ep, tid, bid);                 // BAR3 (h2_cur ready)
      {
        const u16* ah = h_hi + (2*2+cur)*BH_ + kq*256 + ke*8;
        const u16* al = h_lo + (2*2+cur)*BH_ + kq*256 + ke*8;
        f32x4 dacc[4];
#pragma unroll
        for (int a = 0; a < 4; ++a) dacc[a] = (f32x4){0,0,0,0};
#pragma unroll
        for (int kc = 0; kc < 8; ++kc){
          const bf16x8 wd = ld8(WD + (size_t)(ct*16 + r16)*1024 + kq*256 + kc*32 + ke*8);
#pragma unroll
          for (int bt = 0; bt < 4; ++bt){
            const int ao = (bh*64 + bt*16 + r16)*H_ + kc*32;
            dacc[bt] = MFMA(ld8(ah + ao), wd, dacc[bt]);
            dacc[bt] = MFMA(ld8(al + ao), wd, dacc[bt]);
          }
        }
#pragma unroll
        for (int bt = 0; bt < 4; ++bt)
#pragma unroll
          for (int r = 0; r < 4; ++r)
            red[w][bt*16 + ke*4 + r][r16] = dacc[bt][r];
        __syncthreads();
#pragma unroll
        for (int j = 0; j < 4; ++j){
          const int b = bq*4 + j;
          float v = bd;
#pragma unroll
          for (int k4 = 0; k4 < 4; ++k4) v += red[(b>>6)*4 + k4][b & 63][u];
          const int f = ct*16 + u;
          if (f < F_){
            out[(size_t)b*TF_ + (size_t)t*F_ + f] = v;
            if (t + 1 < T_){
              const bool gt = (((t+1) % 10) < 5);
              const float in = gt ? x[(size_t)b*TF_ + (size_t)(t+1)*F_ + f] : v;
              const u16 hh = f2bf(in);
              if_hi[b*FX_ + f] = hh;
              if_lo[b*FX_ + f] = f2bf(in - bf2f(hh));
            }
          }
        }
        __syncthreads();
      }
      ++ep; gbar(bar, ep, tid, bid);                 // BAR4
    }
  } else {
    // ---------------- idle blocks: barrier participation only ----------------
    unsigned ep = 0;
    for (int t = 0; t < T_; ++t){
      ++ep; gbar(bar, ep, tid, bid);
      ++ep; gbar(bar, ep, tid, bid);
      ++ep; gbar(bar, ep, tid, bid);
      ++ep; gbar(bar, ep, tid, bid);
    }
  }
}

// ---------- prep: permuted biases, decoder bias, initial in_frame ----------
__global__ void k_prep(const float* __restrict__ x,
                       const float* bi1, const float* bh1,
                       const float* bi2, const float* bh2,
                       const float* bi3, const float* bh3,
                       const float* bd_in,
                       float* __restrict__ bperm, float* __restrict__ bdec,
                       u16* __restrict__ if_hi, u16* __restrict__ if_lo)
{
  const int i = blockIdx.x * blockDim.x + threadIdx.x;
  if (i < 3*G_){
    const int l = i >> 12, r = i & 4095;
    const int ug = r >> 6, g = (r >> 4) & 3, u = r & 15;
    const int j = (g << 10) | (ug << 4) | u;          // original gate row
    const float* bi = (l == 0) ? bi1 : (l == 1) ? bi2 : bi3;
    const float* bh = (l == 0) ? bh1 : (l == 1) ? bh2 : bh3;
    bperm[i] = bi[j] + bh[j];
  }
  const int i2 = i - 3*G_;
  if (i2 >= 0 && i2 < 192) bdec[i2] = (i2 < F_) ? bd_in[i2] : 0.f;
  const int i3 = i2 - 192;
  if (i3 >= 0 && i3 < B_*FX_){
    const int b = i3 >> 8, f = i3 & 255;
    const float v = (f < F_) ? x[(size_t)b*TF_ + f] : 0.f;   // t=0 is ground-truth
    const u16 hh = f2bf(v);
    if_hi[i3] = hh;
    if_lo[i3] = f2bf(v - bf2f(hh));
  }
}

// ---------- weight convert: fp32 -> bf16, gate-permuted ----------
__global__ void k_wcvt(const float* __restrict__ Wih1, const float* __restrict__ Whh1,
                       const float* __restrict__ Wih2, const float* __restrict__ Whh2,
                       const float* __restrict__ Wih3, const float* __restrict__ Whh3,
                       const float* __restrict__ Wd_in,
                       u16* __restrict__ W1X, u16* __restrict__ W1H,
                       u16* __restrict__ W2,  u16* __restrict__ W3,
                       u16* __restrict__ WD)
{
  const int region = blockIdx.y;
  const size_t stride = (size_t)gridDim.x * blockDim.x;
  const size_t i0 = (size_t)blockIdx.x * blockDim.x + threadIdx.x;
  if (region == 0){
    for (size_t i = i0; i < (size_t)G_*FX_; i += stride){
      const int r = (int)(i >> 8), k = (int)(i & 255);
      const int ug = r >> 6, g = (r >> 4) & 3, u = r & 15;
      const int j = (g << 10) | (ug << 4) | u;
      W1X[i] = f2bf((k < F_) ? Wih1[(size_t)j*F_ + k] : 0.f);
    }
  } else if (region == 1){
    for (size_t i = i0; i < (size_t)G_*H_; i += stride){
      const int r = (int)(i >> 10), k = (int)(i & 1023);
      const int ug = r >> 6, g = (r >> 4) & 3, u = r & 15;
      const int j = (g << 10) | (ug << 4) | u;
      W1H[i] = f2bf(Whh1[(size_t)j*H_ + k]);
    }
  } else if (region == 2){
    for (size_t i = i0; i < (size_t)G_*2048; i += stride){
      const int r = (int)(i >> 11), k = (int)(i & 2047);
      const int ug = r >> 6, g = (r >> 4) & 3, u = r & 15;
      const int j = (g << 10) | (ug << 4) | u;
      W2[i] = f2bf((k < H_) ? Wih2[(size_t)j*H_ + k] : Whh2[(size_t)j*H_ + (k - H_)]);
    }
  } else if (region == 3){
    for (size_t i = i0; i < (size_t)G_*2048; i += stride){
      const int r = (int)(i >> 11), k = (int)(i & 2047);
      const int ug = r >> 6, g = (r >> 4) & 3, u = r & 15;
      const int j = (g << 10) | (ug << 4) | u;
      W3[i] = f2bf((k < H_) ? Wih3[(size_t)j*H_ + k] : Whh3[(size_t)j*H_ + (k - H_)]);
    }
  } else {
    for (size_t i = i0; i < (size_t)176*H_; i += stride){
      const int r = (int)(i >> 10), k = (int)(i & 1023);
      WD[i] = f2bf((r < F_) ? Wd_in[(size_t)r*H_ + k] : 0.f);
    }
  }
}

extern "C" void kernel_launch(void* const* d_in, const int* in_sizes, int n_in,
                              void* d_out, int out_size, void* d_ws, size_t ws_size,
                              hipStream_t stream)
{
  const float* x    = (const float*)d_in[0];
  const float* Wih1 = (const float*)d_in[1];
  const float* bih1 = (const float*)d_in[2];
  const float* Whh1 = (const float*)d_in[3];
  const float* bhh1 = (const float*)d_in[4];
  const float* Wih2 = (const float*)d_in[5];
  const float* bih2 = (const float*)d_in[6];
  const float* Whh2 = (const float*)d_in[7];
  const float* bhh2 = (const float*)d_in[8];
  const float* Wih3 = (const float*)d_in[9];
  const float* bih3 = (const float*)d_in[10];
  const float* Whh3 = (const float*)d_in[11];
  const float* bhh3 = (const float*)d_in[12];
  const float* Wdec = (const float*)d_in[13];
  const float* bdec_in = (const float*)d_in[14];
  float* out = (float*)d_out;

  char* ws = (char*)d_ws;
  size_t off = 0;
  auto alloc = [&](size_t bytes) -> void* {
    void* p = ws + off;
    off = (off + bytes + 255) & ~(size_t)255;
    return p;
  };
  unsigned* bar = (unsigned*)alloc(4096);        // 16 leaves + root, 64B-spaced
  u16* h_hi  = (u16*)alloc((size_t)3*2*BH_*2);
  u16* h_lo  = (u16*)alloc((size_t)3*2*BH_*2);
  u16* if_hi = (u16*)alloc((size_t)B_*FX_*2);
  u16* if_lo = (u16*)alloc((size_t)B_*FX_*2);
  const size_t zero_bytes = off;                 // state zone: re-zeroed every launch
  u16* W1X = (u16*)alloc((size_t)G_*FX_*2);
  u16* W1H = (u16*)alloc((size_t)G_*H_*2);
  u16* W2  = (u16*)alloc((size_t)G_*2048*2);
  u16* W3  = (u16*)alloc((size_t)G_*2048*2);
  u16* WD  = (u16*)alloc((size_t)176*H_*2);
  float* bperm = (float*)alloc((size_t)3*G_*4);
  float* bdec  = (float*)alloc((size_t)192*4);

  hipMemsetAsync(d_ws, 0, zero_bytes, stream);
  k_prep<<<180, 256, 0, stream>>>(x, bih1, bhh1, bih2, bhh2, bih3, bhh3, bdec_in,
                                  bperm, bdec, if_hi, if_lo);
  k_wcvt<<<dim3(2048, 5), 256, 0, stream>>>(Wih1, Whh1, Wih2, Whh2, Wih3, Whh3, Wdec,
                                            W1X, W1H, W2, W3, WD);
  k_main<<<NB_, NT_, 0, stream>>>(x, out, W1X, W1H, W2, W3, WD, bperm, bdec,
                                  h_hi, h_lo, if_hi, if_lo, bar);
}